// Round 4
// baseline (453.362 us; speedup 1.0000x reference)
//
#include <hip/hip_runtime.h>
#include <cstddef>

// EdgeAttention: fused Sobel-edge -> depthwise3x3 -> BN(eval) -> ReLU
// B=16, C=256, H=128, W=128, fp32.
// R7 = R6 with the nontemporal-store compile fix (native clang vector type;
// __builtin_nontemporal_store rejects HIP_vector_type classes).
// R6 theory: R5's 8192 co-resident waves span the whole 537 MB footprint ->
// DRAM row-buffer thrash (~3.9 TB/s vs 6.5 TB/s fills). RSTRIP 64 -> 16
// gives 32768 waves (4x oversubscription): resident cohort ~134 MB compact
// window marching in 4 sweeps. Halo reads overlap between concurrent strips
// of the same image -> L2/L3 hits. Non-temporal stores keep the write
// stream from evicting shared halo lines.

#define BB 16
#define CC 256
#define HH 128
#define WW 128
#define RSTRIP 16                 // rows per wave strip
#define NSTRIP (HH / RSTRIP)      // 8 strips per (b,c) image
#define EPS 1e-5f

typedef float f32x2 __attribute__((ext_vector_type(2)));

struct DS { float dA, dB, sA, sB; };   // per-row Sobel row-combos
struct ER { float el, eA, eB, er; };   // edge row: left halo, e0, e1, right halo

__device__ __forceinline__ void xrow_load(const float* __restrict__ xp, int j,
                                          int lane, float& a0, float& a1) {
    if ((unsigned)j < (unsigned)HH) {
        const float2 v = *(const float2*)(xp + (size_t)j * WW + (lane << 1));
        a0 = v.x; a1 = v.y;
    } else {
        a0 = 0.f; a1 = 0.f;
    }
}

// Horizontal Sobel combos for one x-row. Lane i holds cols 2i, 2i+1.
//   dX = (right - left), sX = (left + 2*center + right)
__device__ __forceinline__ DS make_ds(float a0, float a1, int lane) {
    float xl = __shfl(a1, lane - 1, 64);   // col 2i-1 (lane i-1's a1)
    float xr = __shfl(a0, lane + 1, 64);   // col 2i+2 (lane i+1's a0)
    xl = (lane == 0)  ? 0.f : xl;          // image left pad
    xr = (lane == 63) ? 0.f : xr;          // image right pad
    DS d;
    d.dA = a1 - xl;
    d.dB = xr - a0;
    d.sA = xl + 2.f * a0 + a1;
    d.sB = a0 + 2.f * a1 + xr;
    return d;
}

// Edge row k from ds rows k-1 (p), k (q), k+1 (t).
__device__ __forceinline__ ER make_edge(const DS& p, const DS& q, const DS& t,
                                        int lane) {
    float gxA = p.dA + 2.f * q.dA + t.dA;
    float gxB = p.dB + 2.f * q.dB + t.dB;
    float gyA = t.sA - p.sA;
    float gyB = t.sB - p.sB;
    ER e;
    e.eA = 0.5f * (fabsf(gxA) + fabsf(gyA));
    e.eB = 0.5f * (fabsf(gxB) + fabsf(gyB));
    float el = __shfl(e.eB, lane - 1, 64); // edge col 2i-1
    float er = __shfl(e.eA, lane + 1, 64); // edge col 2i+2
    e.el = (lane == 0)  ? 0.f : el;
    e.er = (lane == 63) ? 0.f : er;
    return e;
}

__global__ __launch_bounds__(256) void edge_attn_reg(
    const float* __restrict__ x,
    const float* __restrict__ dw,
    const float* __restrict__ gamma,
    const float* __restrict__ beta,
    const float* __restrict__ mean,
    const float* __restrict__ var,
    float* __restrict__ out)
{
    const int lane = threadIdx.x & 63;
    const int wid  = (blockIdx.x << 2) + (threadIdx.x >> 6); // global wave id
    const int bc   = wid >> 3;                 // b*C + c   (NSTRIP == 8)
    const int y0   = (wid & (NSTRIP - 1)) * RSTRIP;
    const int c    = bc & (CC - 1);

    const float* __restrict__ xp = x   + (size_t)bc * (HH * WW);
    float* __restrict__       op = out + (size_t)bc * (HH * WW);

    const float* __restrict__ wp = dw + c * 9;
    const float w0 = wp[0], w1 = wp[1], w2 = wp[2];
    const float w3 = wp[3], w4 = wp[4], w5 = wp[5];
    const float w6 = wp[6], w7 = wp[7], w8 = wp[8];
    const float inv  = gamma[c] / sqrtf(var[c] + EPS);
    const float bias = beta[c] - mean[c] * inv;

    // ---- prologue: x rows y0-2 .. y0+3; ds rows; edge rows y0-1, y0 ----
    float p0a, p0b, p1a, p1b, p2a, p2b, p3a, p3b;
    float xa, xb;   // x row r+2 at loop head
    float ya, yb;   // x row r+3 at loop head
    xrow_load(xp, y0 - 2, lane, p0a, p0b);
    xrow_load(xp, y0 - 1, lane, p1a, p1b);
    xrow_load(xp, y0,     lane, p2a, p2b);
    xrow_load(xp, y0 + 1, lane, p3a, p3b);
    xrow_load(xp, y0 + 2, lane, xa, xb);
    xrow_load(xp, y0 + 3, lane, ya, yb);

    DS dsA = make_ds(p0a, p0b, lane);          // row y0-2
    DS dsB = make_ds(p1a, p1b, lane);          // row y0-1
    DS d0  = make_ds(p2a, p2b, lane);          // row y0
    DS d1  = make_ds(p3a, p3b, lane);          // row y0+1

    ER e_m;                                    // edge row y0-1 (zero pad at top)
    if (y0 > 0) e_m = make_edge(dsA, dsB, d0, lane);
    else        { e_m.el = e_m.eA = e_m.eB = e_m.er = 0.f; }
    ER e_c = make_edge(dsB, d0, d1, lane);     // edge row y0

    // last x row this strip needs:
    const int jlim       = (y0 + RSTRIP + 1 < HH) ? (y0 + RSTRIP + 1) : (HH - 1);
    const int steady_end = jlim - 3;           // r+4 <= jlim in steady loop

    // ---- steady state: branch-free, 2-deep prefetch, unrolled ----
    #pragma unroll 4
    for (int r = y0; r < steady_end; ++r) {
        // load row r+4 (consumed 2 iterations later) -- always in-range here
        const float2 nv = *(const float2*)(xp + (size_t)(r + 4) * WW + (lane << 1));

        DS d2 = make_ds(xa, xb, lane);         // row r+2
        ER e_p = make_edge(d0, d1, d2, lane);  // edge row r+1 (in-range here)

        float o0 = w0 * e_m.el + w1 * e_m.eA + w2 * e_m.eB
                 + w3 * e_c.el + w4 * e_c.eA + w5 * e_c.eB
                 + w6 * e_p.el + w7 * e_p.eA + w8 * e_p.eB;
        float o1 = w0 * e_m.eA + w1 * e_m.eB + w2 * e_m.er
                 + w3 * e_c.eA + w4 * e_c.eB + w5 * e_c.er
                 + w6 * e_p.eA + w7 * e_p.eB + w8 * e_p.er;
        o0 = fmaxf(o0 * inv + bias, 0.f);
        o1 = fmaxf(o1 * inv + bias, 0.f);
        f32x2 ov; ov.x = o0; ov.y = o1;
        __builtin_nontemporal_store(ov,
            (f32x2*)(op + (size_t)r * WW + (lane << 1)));

        // rotate rings (named regs -> pure renames after unroll)
        d0 = d1; d1 = d2;
        e_m = e_c; e_c = e_p;
        xa = ya; xb = yb;
        ya = nv.x; yb = nv.y;
    }

    // ---- epilogue: last few rows (no more loads; bottom zero-pad) ----
    for (int r = steady_end; r < y0 + RSTRIP; ++r) {
        DS d2 = make_ds(xa, xb, lane);         // row r+2 (zeros if past jlim ring)
        ER e_p;
        if (r + 1 < HH) e_p = make_edge(d0, d1, d2, lane);
        else            { e_p.el = e_p.eA = e_p.eB = e_p.er = 0.f; }

        float o0 = w0 * e_m.el + w1 * e_m.eA + w2 * e_m.eB
                 + w3 * e_c.el + w4 * e_c.eA + w5 * e_c.eB
                 + w6 * e_p.el + w7 * e_p.eA + w8 * e_p.eB;
        float o1 = w0 * e_m.eA + w1 * e_m.eB + w2 * e_m.er
                 + w3 * e_c.eA + w4 * e_c.eB + w5 * e_c.er
                 + w6 * e_p.eA + w7 * e_p.eB + w8 * e_p.er;
        o0 = fmaxf(o0 * inv + bias, 0.f);
        o1 = fmaxf(o1 * inv + bias, 0.f);
        f32x2 ov; ov.x = o0; ov.y = o1;
        __builtin_nontemporal_store(ov,
            (f32x2*)(op + (size_t)r * WW + (lane << 1)));

        d0 = d1; d1 = d2;
        e_m = e_c; e_c = e_p;
        xa = ya; xb = yb;
        ya = 0.f; yb = 0.f;                    // rows past jlim are zero pad
    }
}

extern "C" void kernel_launch(void* const* d_in, const int* in_sizes, int n_in,
                              void* d_out, int out_size, void* d_ws, size_t ws_size,
                              hipStream_t stream) {
    const float* x     = (const float*)d_in[0];
    const float* dw    = (const float*)d_in[1];
    const float* gamma = (const float*)d_in[2];
    const float* beta  = (const float*)d_in[3];
    const float* mean  = (const float*)d_in[4];
    const float* var   = (const float*)d_in[5];
    float* out = (float*)d_out;

    // 16*256 images * 8 strips = 32768 waves -> 8192 blocks of 4 waves
    // (4x oversubscription -> compact marching address window)
    const int nblocks = (BB * CC * NSTRIP) / 4;
    edge_attn_reg<<<nblocks, 256, 0, stream>>>(x, dw, gamma, beta, mean, var, out);
}

// Round 7
// 448.218 us; speedup vs baseline: 1.0115x; 1.0115x over previous
//
#include <hip/hip_runtime.h>
#include <cstddef>

// EdgeAttention: fused Sobel-edge -> depthwise3x3 -> BN(eval) -> ReLU
// B=16, C=256, H=128, W=128, fp32.
// R9 (resubmit; previous round was an infra failure, no signal):
// R3's bulk-staged LDS structure (supply-healthy memory engine) with its
// one quantified killer removed: the 6 scalar LDS halo reads per stencil iter
// (8-way bank conflict, 58% of R3 runtime) become __shfl(lane+-1) bpermutes
// (conflict-free crossbar, semantics verified in R4/R5/R7). All row-validity
// guards are branchless selects so every cross-lane op runs under FULL exec
// (R8's DPP fail was possibly exec-mask related; this kills that class).
// LDS rows are compact 512B (no halo slots) -> b128 reads ~conflict-free.

#define BB 16
#define CC 256
#define HH 128
#define WW 128
#define TY 16            // output rows per block
#define XROWS (TY + 4)   // 20 x rows incl. halo 2
#define EROWS (TY + 2)   // 18 edge rows incl. halo 1
#define EPS 1e-5f

typedef float f32x4 __attribute__((ext_vector_type(4)));

__global__ __launch_bounds__(256) void edge_attn_fused(
    const float* __restrict__ x,
    const float* __restrict__ dw,
    const float* __restrict__ gamma,
    const float* __restrict__ beta,
    const float* __restrict__ mean,
    const float* __restrict__ var,
    float* __restrict__ out)
{
    __shared__ __align__(16) float sx[XROWS * WW];   // 10240 B
    __shared__ __align__(16) float se[EROWS * WW];   //  9216 B

    const int tid  = threadIdx.x;
    const int lane = tid & 63;
    const int tile = blockIdx.x & 7;      // 8 row-tiles per image
    const int bc   = blockIdx.x >> 3;     // b*C + c
    const int c    = bc & (CC - 1);
    const int y0   = tile * TY;

    const float* __restrict__ xp = x + (size_t)bc * (HH * WW);

    // ---- stage 1: bulk-stage 20 rows x 128 cols into LDS ----
    // 640 float4 slots / 256 threads: clustered loads (deep MLP), then write.
    // Rows outside the image are zero-filled (needed: stage 2 reads them
    // unconditionally under full exec).
    {
        const int i0 = tid, i1 = tid + 256, i2 = tid + 512;
        float4 v0 = make_float4(0.f, 0.f, 0.f, 0.f);
        float4 v1 = v0, v2 = v0;
        int gr0 = y0 - 2 + (i0 >> 5);
        int gr1 = y0 - 2 + (i1 >> 5);
        int gr2 = y0 - 2 + (i2 >> 5);
        if ((unsigned)gr0 < (unsigned)HH)
            v0 = *(const float4*)(xp + gr0 * WW + ((i0 & 31) << 2));
        if ((unsigned)gr1 < (unsigned)HH)
            v1 = *(const float4*)(xp + gr1 * WW + ((i1 & 31) << 2));
        if (i2 < XROWS * 32 && (unsigned)gr2 < (unsigned)HH)
            v2 = *(const float4*)(xp + gr2 * WW + ((i2 & 31) << 2));
        *(float4*)(&sx[(i0 >> 5) * WW + ((i0 & 31) << 2)]) = v0;
        *(float4*)(&sx[(i1 >> 5) * WW + ((i1 & 31) << 2)]) = v1;
        if (i2 < XROWS * 32)
            *(float4*)(&sx[(i2 >> 5) * WW + ((i2 & 31) << 2)]) = v2;
    }
    __syncthreads();

    // ---- stage 2: Sobel -> edge LDS; branchless, full-exec shuffles ----
    for (int i = tid; i < EROWS * 32; i += 256) {
        int r   = i >> 5;                 // edge row; x-tile rows r, r+1, r+2
        int cc4 = i & 31;
        int ger = y0 - 1 + r;

        const float* p0 = &sx[r * WW + (cc4 << 2)];
        float4 m0 = *(const float4*)(p0);
        float4 m1 = *(const float4*)(p0 + WW);
        float4 m2 = *(const float4*)(p0 + 2 * WW);

        float lt0 = __shfl(m0.w, lane - 1, 64);
        float lt1 = __shfl(m1.w, lane - 1, 64);
        float lt2 = __shfl(m2.w, lane - 1, 64);
        float rt0 = __shfl(m0.x, lane + 1, 64);
        float rt1 = __shfl(m1.x, lane + 1, 64);
        float rt2 = __shfl(m2.x, lane + 1, 64);
        lt0 = (cc4 == 0)  ? 0.f : lt0;    // image left border (and row seam)
        lt1 = (cc4 == 0)  ? 0.f : lt1;
        lt2 = (cc4 == 0)  ? 0.f : lt2;
        rt0 = (cc4 == 31) ? 0.f : rt0;    // image right border (and row seam)
        rt1 = (cc4 == 31) ? 0.f : rt1;
        rt2 = (cc4 == 31) ? 0.f : rt2;

        float4 ev;
        #define SOB(a0l,a0c,a0r,a1l,a1r,a2l,a2c,a2r) \
            (0.5f * (fabsf(((a0r)-(a0l)) + 2.f*((a1r)-(a1l)) + ((a2r)-(a2l))) \
                   + fabsf(((a2l)-(a0l)) + 2.f*((a2c)-(a0c)) + ((a2r)-(a0r)))))
        ev.x = SOB(lt0, m0.x, m0.y,  lt1, m1.y,  lt2, m2.x, m2.y);
        ev.y = SOB(m0.x, m0.y, m0.z, m1.x, m1.z, m2.x, m2.y, m2.z);
        ev.z = SOB(m0.y, m0.z, m0.w, m1.y, m1.w, m2.y, m2.z, m2.w);
        ev.w = SOB(m0.z, m0.w, rt0,  m1.z, rt1,  m2.z, m2.w, rt2);
        #undef SOB

        // edge rows outside the image are ZERO (second conv's zero padding),
        // even though the zero-padded x rows would give a nonzero stencil.
        const float vm = ((unsigned)ger < (unsigned)HH) ? 1.f : 0.f;
        ev.x *= vm; ev.y *= vm; ev.z *= vm; ev.w *= vm;

        *(float4*)(&se[r * WW + (cc4 << 2)]) = ev;
    }
    __syncthreads();

    // ---- stage 3: depthwise 3x3 + BN + ReLU, float4 nt-store ----
    const float* __restrict__ wp = dw + c * 9;
    const float w0 = wp[0], w1 = wp[1], w2 = wp[2];
    const float w3 = wp[3], w4 = wp[4], w5 = wp[5];
    const float w6 = wp[6], w7 = wp[7], w8 = wp[8];
    const float inv  = gamma[c] / sqrtf(var[c] + EPS);
    const float bias = beta[c] - mean[c] * inv;

    float* __restrict__ op = out + (size_t)bc * (HH * WW) + y0 * WW;

    for (int i = tid; i < TY * 32; i += 256) {
        int r   = i >> 5;                 // output row; edge rows r, r+1, r+2
        int cc4 = i & 31;
        const float* p0 = &se[r * WW + (cc4 << 2)];
        float4 m0 = *(const float4*)(p0);
        float4 m1 = *(const float4*)(p0 + WW);
        float4 m2 = *(const float4*)(p0 + 2 * WW);

        float lt0 = __shfl(m0.w, lane - 1, 64);
        float lt1 = __shfl(m1.w, lane - 1, 64);
        float lt2 = __shfl(m2.w, lane - 1, 64);
        float rt0 = __shfl(m0.x, lane + 1, 64);
        float rt1 = __shfl(m1.x, lane + 1, 64);
        float rt2 = __shfl(m2.x, lane + 1, 64);
        lt0 = (cc4 == 0)  ? 0.f : lt0;
        lt1 = (cc4 == 0)  ? 0.f : lt1;
        lt2 = (cc4 == 0)  ? 0.f : lt2;
        rt0 = (cc4 == 31) ? 0.f : rt0;
        rt1 = (cc4 == 31) ? 0.f : rt1;
        rt2 = (cc4 == 31) ? 0.f : rt2;

        f32x4 o;
        o.x = w0*lt0  + w1*m0.x + w2*m0.y + w3*lt1  + w4*m1.x + w5*m1.y + w6*lt2  + w7*m2.x + w8*m2.y;
        o.y = w0*m0.x + w1*m0.y + w2*m0.z + w3*m1.x + w4*m1.y + w5*m1.z + w6*m2.x + w7*m2.y + w8*m2.z;
        o.z = w0*m0.y + w1*m0.z + w2*m0.w + w3*m1.y + w4*m1.z + w5*m1.w + w6*m2.y + w7*m2.z + w8*m2.w;
        o.w = w0*m0.z + w1*m0.w + w2*rt0  + w3*m1.z + w4*m1.w + w5*rt1  + w6*m2.z + w7*m2.w + w8*rt2;
        o.x = fmaxf(o.x * inv + bias, 0.f);
        o.y = fmaxf(o.y * inv + bias, 0.f);
        o.z = fmaxf(o.z * inv + bias, 0.f);
        o.w = fmaxf(o.w * inv + bias, 0.f);
        __builtin_nontemporal_store(o, (f32x4*)(op + r * WW + (cc4 << 2)));
    }
}

extern "C" void kernel_launch(void* const* d_in, const int* in_sizes, int n_in,
                              void* d_out, int out_size, void* d_ws, size_t ws_size,
                              hipStream_t stream) {
    const float* x     = (const float*)d_in[0];
    const float* dw    = (const float*)d_in[1];
    const float* gamma = (const float*)d_in[2];
    const float* beta  = (const float*)d_in[3];
    const float* mean  = (const float*)d_in[4];
    const float* var   = (const float*)d_in[5];
    float* out = (float*)d_out;

    const int nblocks = BB * CC * (HH / TY);   // 32768
    edge_attn_fused<<<nblocks, 256, 0, stream>>>(x, dw, gamma, beta, mean, var, out);
}